// Round 6
// baseline (113.462 us; speedup 1.0000x reference)
//
#include <hip/hip_runtime.h>

#define TPB 256
#define MAX_BLOCKS 2048   // 8 blocks/CU, 32 waves/CU: R3-proven TLP level.
                          // 1024 (R5) cost ~6 us -- latency-hiding needs the
                          // full wave complement, prefetch alone isn't enough.

// v_sin_f32 computes sin(2*pi*x) -- input in REVOLUTIONS (cdna4_isa.md §3).
// Inputs are in [0,1]: no range reduction needed.
__device__ __forceinline__ float sin2pi(float x) {
    return __builtin_amdgcn_sinf(x);
}

// diff_round(x) = x - sin(2pi x)/(2pi): one v_sin + one v_fma
__device__ __forceinline__ float diff_round(float x) {
    return __builtin_fmaf(sin2pi(x), -0.15915494309189533577f, x);
}

// One v_add_f32_dpp: v += dpp_move(v, CTRL). Pure VALU, no LDS pipe.
template <int CTRL>
__device__ __forceinline__ float dpp_add(float v) {
    int i = __float_as_int(v);
    int m = __builtin_amdgcn_update_dpp(i, i, CTRL, 0xF, 0xF, false);
    return v + __int_as_float(m);
}

// Sum across a 16-lane DPP row (one tile group): 4 VALU instructions.
__device__ __forceinline__ float row_sum16(float s) {
    s = dpp_add<0xB1>(s);   // quad_perm [1,0,3,2]  == xor 1
    s = dpp_add<0x4E>(s);   // quad_perm [2,3,0,1]  == xor 2
    s = dpp_add<0x124>(s);  // row_ror:4
    s = dpp_add<0x128>(s);  // row_ror:8
    return s;
}

// varr for one tile, given this lane's float4 of image and mask.
// Result is uniform across the 16-lane row.
__device__ __forceinline__ float tile_varr(const float4 iv, const float4 mv) {
    float m0 = diff_round(diff_round(mv.x));
    float m1 = diff_round(diff_round(mv.y));
    float m2 = diff_round(diff_round(mv.z));
    float m3 = diff_round(diff_round(mv.w));
    float x0 = iv.x * m0, x1 = iv.y * m1, x2 = iv.z * m2, x3 = iv.w * m3;

    float sm = row_sum16((m0 + m1) + (m2 + m3));
    float sx = row_sum16((x0 + x1) + (x2 + x3));
    // v_rcp_f32 (~1 ulp) vs IEEE div; output threshold 1.5e-2 -- plenty.
    const float inv_msum = __builtin_amdgcn_rcpf(sm + 1e-8f);
    const float mean = sx * inv_msum;

    float d0 = (x0 - mean) * m0;
    float d1 = (x1 - mean) * m1;
    float d2 = (x2 - mean) * m2;
    float d3 = (x3 - mean) * m3;
    float sd = row_sum16((d0 * d0 + d1 * d1) + (d2 * d2 + d3 * d3));
    return sd * inv_msum;
}

// One tile = one (b,n) area = 64 contiguous floats; 16 lanes (one DPP row)
// * float4 per tile; wave covers 4 tiles; block covers 16 per iteration.
// 2048 blocks -> exactly 4 grid-stride iterations, 1-deep load prefetch.
// Each block contributes ONE fp32 atomicAdd (device-coherent, fence-free --
// R4's per-block __threadfence caused an L2-invalidate storm, +50 us).
__global__ __launch_bounds__(TPB) void area_var_atomic(
    const float* __restrict__ img, const float* __restrict__ msk,
    float* __restrict__ out, int ntiles, float inv_count) {
    const int tid  = threadIdx.x;
    const int wave = tid >> 6;      // 0..3
    const int lane = tid & 63;
    const int grp  = lane >> 4;     // which of the wave's 4 tiles (DPP row)
    const int j    = lane & 15;     // lane within tile (one float4 each)

    const int tiles_per_block = (TPB / 64) * 4;  // 16
    const int stride = gridDim.x * tiles_per_block;
    int tile = blockIdx.x * tiles_per_block + wave * 4 + grp;

    float acc = 0.0f;               // row-uniform running sum of varr
    if (tile < ntiles) {
        size_t off = (size_t)tile * 64 + (size_t)j * 4;
        float4 iv = *reinterpret_cast<const float4*>(img + off);
        float4 mv = *reinterpret_cast<const float4*>(msk + off);
        for (;;) {
            const int next = tile + stride;
            const bool more = next < ntiles;
            float4 niv = make_float4(0.f, 0.f, 0.f, 0.f);
            float4 nmv = make_float4(0.f, 0.f, 0.f, 0.f);
            if (more) {                       // prefetch before compute
                size_t noff = (size_t)next * 64 + (size_t)j * 4;
                niv = *reinterpret_cast<const float4*>(img + noff);
                nmv = *reinterpret_cast<const float4*>(msk + noff);
            }
            acc += tile_varr(iv, mv);
            if (!more) break;
            iv = niv; mv = nmv; tile = next;
        }
    }
    // acc uniform within each 16-lane row; sum the wave's 4 rows.
    acc += __shfl_xor(acc, 16, 64);
    acc += __shfl_xor(acc, 32, 64);

    __shared__ float wsum[TPB / 64];
    if (lane == 0) wsum[wave] = acc;
    __syncthreads();
    if (tid == 0) {
        const float bsum = (wsum[0] + wsum[1]) + (wsum[2] + wsum[3]);
        // d_out poison 0xAAAAAAAA == -3.0e-13f: harmless vs 1.5e-2 threshold.
        atomicAdd(out, bsum * inv_count);
    }
}

extern "C" void kernel_launch(void* const* d_in, const int* in_sizes, int n_in,
                              void* d_out, int out_size, void* d_ws, size_t ws_size,
                              hipStream_t stream) {
    const float* img = (const float*)d_in[0];   // sv_area_image [B,N,P,Q] fp32
    const float* msk = (const float*)d_in[1];   // sv_area_mask  [B,N,P,Q] fp32
    float* out = (float*)d_out;                 // scalar fp32
    (void)d_ws; (void)ws_size;

    const int ntiles = in_sizes[0] / 64;        // B*N = 131072
    int nblocks = (ntiles + 15) / 16;
    if (nblocks > MAX_BLOCKS) nblocks = MAX_BLOCKS;

    area_var_atomic<<<nblocks, TPB, 0, stream>>>(img, msk, out, ntiles,
                                                 1.0f / (float)ntiles);
}

// Round 7
// 93.643 us; speedup vs baseline: 1.2116x; 1.2116x over previous
//
#include <hip/hip_runtime.h>

#define TPB 256
#define MAX_BLOCKS 2048

// v_sin_f32 computes sin(2*pi*x) -- input in REVOLUTIONS (cdna4_isa.md §3).
// Inputs are in [0,1]: no range reduction needed.
__device__ __forceinline__ float sin2pi(float x) {
    return __builtin_amdgcn_sinf(x);
}

// diff_round(x) = x - sin(2pi x)/(2pi): one v_sin + one v_fma
__device__ __forceinline__ float diff_round(float x) {
    return __builtin_fmaf(sin2pi(x), -0.15915494309189533577f, x);
}

// One v_add_f32_dpp: v += dpp_move(v, CTRL). Pure VALU, no LDS pipe.
template <int CTRL>
__device__ __forceinline__ float dpp_add(float v) {
    int i = __float_as_int(v);
    int m = __builtin_amdgcn_update_dpp(i, i, CTRL, 0xF, 0xF, false);
    return v + __int_as_float(m);
}

// Sum across a 16-lane DPP row: 4 VALU instructions, serial-dependent.
__device__ __forceinline__ float row_sum16(float s) {
    s = dpp_add<0xB1>(s);   // quad_perm [1,0,3,2]  == xor 1
    s = dpp_add<0x4E>(s);   // quad_perm [2,3,0,1]  == xor 2
    s = dpp_add<0x124>(s);  // row_ror:4
    s = dpp_add<0x128>(s);  // row_ror:8
    return s;
}

// varr for one tile; result uniform across the 16-lane row. Two calls on
// independent tiles interleave in the scheduler, halving exposed DPP/sin
// chain latency (R6: kernel was latency-bound at VALUBusy 11%).
__device__ __forceinline__ float tile_varr(const float4 iv, const float4 mv) {
    float m0 = diff_round(diff_round(mv.x));
    float m1 = diff_round(diff_round(mv.y));
    float m2 = diff_round(diff_round(mv.z));
    float m3 = diff_round(diff_round(mv.w));
    float x0 = iv.x * m0, x1 = iv.y * m1, x2 = iv.z * m2, x3 = iv.w * m3;

    float sm = row_sum16((m0 + m1) + (m2 + m3));
    float sx = row_sum16((x0 + x1) + (x2 + x3));
    const float inv_msum = __builtin_amdgcn_rcpf(sm + 1e-8f);  // ~1 ulp, thr 1.5e-2
    const float mean = sx * inv_msum;

    float d0 = (x0 - mean) * m0;
    float d1 = (x1 - mean) * m1;
    float d2 = (x2 - mean) * m2;
    float d3 = (x3 - mean) * m3;
    float sd = row_sum16((d0 * d0 + d1 * d1) + (d2 * d2 + d3 * d3));
    return sd * inv_msum;
}

__device__ __forceinline__ void load_pair(const float* __restrict__ img,
                                          const float* __restrict__ msk,
                                          int t0, int ntiles, int j,
                                          float4& ivA, float4& mvA,
                                          float4& ivB, float4& mvB) {
    ivA = mvA = ivB = mvB = make_float4(0.f, 0.f, 0.f, 0.f);
    const size_t off = (size_t)t0 * 64 + (size_t)j * 4;
    if (t0 < ntiles) {
        ivA = *reinterpret_cast<const float4*>(img + off);
        mvA = *reinterpret_cast<const float4*>(msk + off);
    }
    if (t0 + 1 < ntiles) {          // tile B = t0+1, 64 floats further
        ivB = *reinterpret_cast<const float4*>(img + off + 64);
        mvB = *reinterpret_cast<const float4*>(msk + off + 64);
    }
}

// Each 16-lane row handles TWO adjacent tiles concurrently (2x ILP on the
// serial DPP/sin chains, 2x loads in flight); wave = 8 tiles, block = 32.
// Depth-1 prefetch on top: 8 KB in flight per wave in steady state (was 2 KB
// in R6 -- the latency-bound culprit). Tail: per-block partial store + a
// tiny second dispatch (R3-proven; no fences, no same-address atomic storm).
__global__ __launch_bounds__(TPB) void area_var_partial(
    const float* __restrict__ img, const float* __restrict__ msk,
    float* __restrict__ partial, int ntiles) {
    const int tid  = threadIdx.x;
    const int wave = tid >> 6;      // 0..3
    const int lane = tid & 63;
    const int grp  = lane >> 4;     // DPP row within wave
    const int j    = lane & 15;     // float4 index within tile

    const int tiles_per_block = (TPB / 64) * 4 * 2;  // 32
    const int stride = gridDim.x * tiles_per_block;
    int t0 = blockIdx.x * tiles_per_block + (wave * 4 + grp) * 2;

    float acc = 0.0f;               // row-uniform
    if (t0 < ntiles) {
        float4 ivA, mvA, ivB, mvB;
        load_pair(img, msk, t0, ntiles, j, ivA, mvA, ivB, mvB);
        for (;;) {
            const int nt = t0 + stride;
            const bool more = nt < ntiles;
            float4 nivA, nmvA, nivB, nmvB;
            nivA = nmvA = nivB = nmvB = make_float4(0.f, 0.f, 0.f, 0.f);
            if (more)               // prefetch next pair before compute
                load_pair(img, msk, nt, ntiles, j, nivA, nmvA, nivB, nmvB);
            acc += tile_varr(ivA, mvA);   // two independent chains --
            acc += tile_varr(ivB, mvB);   // scheduler interleaves them
            if (!more) break;
            ivA = nivA; mvA = nmvA; ivB = nivB; mvB = nmvB; t0 = nt;
        }
    }
    // acc uniform per row; sum the wave's 4 rows, then the block's 4 waves.
    acc += __shfl_xor(acc, 16, 64);
    acc += __shfl_xor(acc, 32, 64);

    __shared__ float wsum[TPB / 64];
    if (lane == 0) wsum[wave] = acc;
    __syncthreads();
    if (tid == 0) partial[blockIdx.x] = (wsum[0] + wsum[1]) + (wsum[2] + wsum[3]);
}

__global__ __launch_bounds__(TPB) void final_reduce(
    const float* __restrict__ partial, float* __restrict__ out,
    int n, float inv_count) {
    float s = 0.f;
    for (int i = threadIdx.x; i < n; i += TPB) s += partial[i];
    #pragma unroll
    for (int d = 1; d < 64; d <<= 1) s += __shfl_xor(s, d, 64);
    __shared__ float wsum[TPB / 64];
    const int wave = threadIdx.x >> 6;
    const int lane = threadIdx.x & 63;
    if (lane == 0) wsum[wave] = s;
    __syncthreads();
    if (threadIdx.x == 0)
        out[0] = ((wsum[0] + wsum[1]) + (wsum[2] + wsum[3])) * inv_count;
}

extern "C" void kernel_launch(void* const* d_in, const int* in_sizes, int n_in,
                              void* d_out, int out_size, void* d_ws, size_t ws_size,
                              hipStream_t stream) {
    const float* img = (const float*)d_in[0];   // sv_area_image [B,N,P,Q] fp32
    const float* msk = (const float*)d_in[1];   // sv_area_mask  [B,N,P,Q] fp32
    float* out = (float*)d_out;                 // scalar fp32
    float* partial = (float*)d_ws;

    const int ntiles = in_sizes[0] / 64;        // B*N = 131072
    int nblocks = (ntiles + 31) / 32;
    if (nblocks > MAX_BLOCKS) nblocks = MAX_BLOCKS;  // 2048 -> exactly 2 iters

    area_var_partial<<<nblocks, TPB, 0, stream>>>(img, msk, partial, ntiles);
    final_reduce<<<1, TPB, 0, stream>>>(partial, out, nblocks,
                                        1.0f / (float)ntiles);
}